// Round 2
// baseline (298.309 us; speedup 1.0000x reference)
//
#include <hip/hip_runtime.h>
#include <hip/hip_bf16.h>
#include <float.h>

#define N_PRED 8192
#define M_TGT  16384
#define KD     128
#define TOPK   5
#define ROWS_PER_BLOCK 16
#define WAVES  8
#define MCHUNK (M_TGT / WAVES)   // 2048 targets per wave

using short8  = __attribute__((ext_vector_type(8))) short;
using floatx4 = __attribute__((ext_vector_type(4))) float;

__device__ __forceinline__ unsigned short f2bf(float v) {
    unsigned int u = __float_as_uint(v);
    u = (u + 0x7FFFu + ((u >> 16) & 1u)) >> 16;
    return (unsigned short)u;
}

// ---- prep: bf16 casts (pred pre-scaled by -2), fp32 norms, zero acc ----------
__global__ void prep_kernel(const float* __restrict__ pred,
                            const float* __restrict__ tgt,
                            unsigned short* __restrict__ predB,
                            unsigned short* __restrict__ tgtB,
                            float* __restrict__ a2,
                            float* __restrict__ b2,
                            float* __restrict__ acc) {
    const int row  = blockIdx.x * 4 + (threadIdx.x >> 6);
    const int lane = threadIdx.x & 63;
    const float* src;
    unsigned short* dst;
    float scale;
    float* norm;
    if (row < N_PRED) {
        src = pred + (size_t)row * KD;
        dst = predB + (size_t)row * KD;
        scale = -2.0f;                    // fold "-2 a.b" into A
        norm = a2 + row;
    } else {
        const int rr = row - N_PRED;
        src = tgt + (size_t)rr * KD;
        dst = tgtB + (size_t)rr * KD;
        scale = 1.0f;
        norm = b2 + rr;
    }
    const float2 x = *reinterpret_cast<const float2*>(src + lane * 2);
    unsigned int packed = (unsigned int)f2bf(x.x * scale) |
                          ((unsigned int)f2bf(x.y * scale) << 16);
    *reinterpret_cast<unsigned int*>(dst + lane * 2) = packed;
    float s = x.x * x.x + x.y * x.y;      // norms from ORIGINAL fp32
    #pragma unroll
    for (int off = 32; off > 0; off >>= 1) s += __shfl_down(s, off);
    if (lane == 0) norm[0] = s;
    if (blockIdx.x == 0 && threadIdx.x == 0) acc[0] = 0.0f;
}

// ---- main: MFMA distances + med3 streaming top-5 of (d^2 - |a|^2) ------------
__global__ __launch_bounds__(512, 4) void density_kernel(
        const unsigned short* __restrict__ predB,
        const unsigned short* __restrict__ tgtB,
        const float* __restrict__ a2,
        const float* __restrict__ b2,
        float* __restrict__ acc) {
    const int tid  = threadIdx.x;
    const int wave = tid >> 6;
    const int lane = tid & 63;
    const int col  = lane & 15;
    const int quad = lane >> 4;
    const int rowBase = blockIdx.x * ROWS_PER_BLOCK;

    short8 afrag[4];
    #pragma unroll
    for (int kf = 0; kf < 4; kf++) {
        const unsigned short* p =
            predB + (size_t)(rowBase + col) * KD + kf * 32 + quad * 8;
        afrag[kf] = *reinterpret_cast<const short8*>(p);
    }

    float t5[4][5];
    #pragma unroll
    for (int rg = 0; rg < 4; rg++)
        #pragma unroll
        for (int j = 0; j < 5; j++)
            t5[rg][j] = FLT_MAX;

    const int mBase = wave * MCHUNK;
    const unsigned short* bp = tgtB + (size_t)(mBase + col) * KD + quad * 8;
    const float* b2p = b2 + mBase + col;

    short8 b0 = *reinterpret_cast<const short8*>(bp);
    short8 b1 = *reinterpret_cast<const short8*>(bp + 32);
    short8 b2v = *reinterpret_cast<const short8*>(bp + 64);
    short8 b3 = *reinterpret_cast<const short8*>(bp + 96);
    float  bq = *b2p;

    for (int it = 0; it < MCHUNK / 16; ++it) {
        const bool last = (it == MCHUNK / 16 - 1);
        const unsigned short* bpn = last ? bp : bp + 16 * KD;
        const float* b2pn = last ? b2p : b2p + 16;
        const short8 n0 = *reinterpret_cast<const short8*>(bpn);
        const short8 n1 = *reinterpret_cast<const short8*>(bpn + 32);
        const short8 n2 = *reinterpret_cast<const short8*>(bpn + 64);
        const short8 n3 = *reinterpret_cast<const short8*>(bpn + 96);
        const float  nq = *b2pn;

        floatx4 c = {bq, bq, bq, bq};     // seed with |b|^2 (|a|^2 deferred)
        c = __builtin_amdgcn_mfma_f32_16x16x32_bf16(afrag[0], b0, c, 0, 0, 0);
        c = __builtin_amdgcn_mfma_f32_16x16x32_bf16(afrag[1], b1, c, 0, 0, 0);
        c = __builtin_amdgcn_mfma_f32_16x16x32_bf16(afrag[2], b2v, c, 0, 0, 0);
        c = __builtin_amdgcn_mfma_f32_16x16x32_bf16(afrag[3], b3, c, 0, 0, 0);

        #pragma unroll
        for (int rg = 0; rg < 4; rg++) {
            const float d = c[rg];
            float* t = t5[rg];
            t[4] = __builtin_amdgcn_fmed3f(d, t[3], t[4]);
            t[3] = __builtin_amdgcn_fmed3f(d, t[2], t[3]);
            t[2] = __builtin_amdgcn_fmed3f(d, t[1], t[2]);
            t[1] = __builtin_amdgcn_fmed3f(d, t[0], t[1]);
            t[0] = fminf(t[0], d);
        }
        b0 = n0; b1 = n1; b2v = n2; b3 = n3; bq = nq;
        bp = bpn; b2p = b2pn;
    }

    __shared__ float sm[ROWS_PER_BLOCK * 128 * 5];   // 40 KB
    __shared__ float sm2[ROWS_PER_BLOCK * 16 * 5];   //  5 KB

    #pragma unroll
    for (int rg = 0; rg < 4; rg++)
        #pragma unroll
        for (int j = 0; j < 5; j++)
            sm[((quad * 4 + rg) * 128 + wave * 16 + col) * 5 + j] = t5[rg][j];
    __syncthreads();

    if (tid < 256) {
        const int r16 = tid >> 4, part = tid & 15;
        float u[5] = {FLT_MAX, FLT_MAX, FLT_MAX, FLT_MAX, FLT_MAX};
        for (int s = 0; s < 8; s++) {
            #pragma unroll
            for (int j = 0; j < 5; j++) {
                const float d = sm[(r16 * 128 + part * 8 + s) * 5 + j];
                u[4] = __builtin_amdgcn_fmed3f(d, u[3], u[4]);
                u[3] = __builtin_amdgcn_fmed3f(d, u[2], u[3]);
                u[2] = __builtin_amdgcn_fmed3f(d, u[1], u[2]);
                u[1] = __builtin_amdgcn_fmed3f(d, u[0], u[1]);
                u[0] = fminf(u[0], d);
            }
        }
        #pragma unroll
        for (int j = 0; j < 5; j++) sm2[(r16 * 16 + part) * 5 + j] = u[j];
    }
    __syncthreads();

    if (tid < 16) {
        float u[5] = {FLT_MAX, FLT_MAX, FLT_MAX, FLT_MAX, FLT_MAX};
        for (int s = 0; s < 16; s++) {
            #pragma unroll
            for (int j = 0; j < 5; j++) {
                const float d = sm2[(tid * 16 + s) * 5 + j];
                u[4] = __builtin_amdgcn_fmed3f(d, u[3], u[4]);
                u[3] = __builtin_amdgcn_fmed3f(d, u[2], u[3]);
                u[2] = __builtin_amdgcn_fmed3f(d, u[1], u[2]);
                u[1] = __builtin_amdgcn_fmed3f(d, u[0], u[1]);
                u[0] = fminf(u[0], d);
            }
        }
        const float a2r = a2[rowBase + tid];
        float hs = 0.0f;
        #pragma unroll
        for (int j = 0; j < 5; j++) {
            const float dd = sqrtf(fmaxf(u[j] + a2r, 0.0f));
            hs += fmaxf(dd - 1.0f, 0.0f);
        }
        #pragma unroll
        for (int off = 8; off > 0; off >>= 1) hs += __shfl_down(hs, off);
        if (tid == 0) atomicAdd(acc, hs);
    }
}

// ---- finalize ----------------------------------------------------------------
__global__ void finalize_kernel(const float* __restrict__ acc, float* __restrict__ out) {
    out[0] = acc[0] * (1.0f / (float)(N_PRED * TOPK));
}

extern "C" void kernel_launch(void* const* d_in, const int* in_sizes, int n_in,
                              void* d_out, int out_size, void* d_ws, size_t ws_size,
                              hipStream_t stream) {
    const float* pred = (const float*)d_in[0];
    const float* tgt  = (const float*)d_in[1];
    char* ws = (char*)d_ws;
    unsigned short* predB = (unsigned short*)(ws);
    unsigned short* tgtB  = (unsigned short*)(ws + (size_t)2 * 1024 * 1024);
    float* a2  = (float*)(ws + (size_t)6 * 1024 * 1024);
    float* b2  = (float*)(ws + (size_t)6 * 1024 * 1024 + 32 * 1024);
    float* acc = (float*)(ws + (size_t)6 * 1024 * 1024 + 96 * 1024);
    float* out = (float*)d_out;

    prep_kernel<<<(N_PRED + M_TGT) / 4, 256, 0, stream>>>(pred, tgt, predB, tgtB, a2, b2, acc);
    density_kernel<<<N_PRED / ROWS_PER_BLOCK, 512, 0, stream>>>(predB, tgtB, a2, b2, acc);
    finalize_kernel<<<1, 1, 0, stream>>>(acc, out);
}

// Round 3
// 134.727 us; speedup vs baseline: 2.2142x; 2.2142x over previous
//
#include <hip/hip_runtime.h>
#include <hip/hip_bf16.h>
#include <float.h>

#define N_PRED 8192
#define M_TGT  16384
#define KD     128
#define TOPK   5
#define SPLITS 8
#define MSPLIT (M_TGT / SPLITS)            // 2048 targets per block
#define TILE_T 64                          // targets per LDS tile
#define NTILES (MSPLIT / TILE_T)           // 32
#define ROWS_PER_BLOCK 256                 // 8 waves x 32 rows
#define ROWBLKS (N_PRED / ROWS_PER_BLOCK)  // 32

using short8  = __attribute__((ext_vector_type(8))) short;
using floatx4 = __attribute__((ext_vector_type(4))) float;

__device__ __forceinline__ unsigned short f2bf(float v) {
    unsigned int u = __float_as_uint(v);
    u = (u + 0x7FFFu + ((u >> 16) & 1u)) >> 16;
    return (unsigned short)u;
}

// async global->LDS, dest = wave-uniform base + lane*size
__device__ __forceinline__ void async16(const void* g, void* l) {
    __builtin_amdgcn_global_load_lds(
        (const __attribute__((address_space(1))) unsigned int*)g,
        (__attribute__((address_space(3))) unsigned int*)l, 16, 0, 0);
}
__device__ __forceinline__ void async4(const void* g, void* l) {
    __builtin_amdgcn_global_load_lds(
        (const __attribute__((address_space(1))) unsigned int*)g,
        (__attribute__((address_space(3))) unsigned int*)l, 4, 0, 0);
}

// sorted ascending top-5 insert: 4x v_med3_f32 + 1x v_min_f32
__device__ __forceinline__ void ins5(float* t, float d) {
    t[4] = __builtin_amdgcn_fmed3f(d, t[3], t[4]);
    t[3] = __builtin_amdgcn_fmed3f(d, t[2], t[3]);
    t[2] = __builtin_amdgcn_fmed3f(d, t[1], t[2]);
    t[1] = __builtin_amdgcn_fmed3f(d, t[0], t[1]);
    t[0] = fminf(t[0], d);
}

// ---- prep: bf16 casts (pred pre-scaled by -2), fp32 norms, zero acc/counter --
// half-wave (32 lanes) per row, float4 per lane
__global__ void prep_kernel(const float* __restrict__ pred,
                            const float* __restrict__ tgt,
                            unsigned short* __restrict__ predB,
                            unsigned short* __restrict__ tgtB,
                            float* __restrict__ a2,
                            float* __restrict__ b2,
                            float* __restrict__ acc,
                            unsigned int* __restrict__ counter) {
    const int row = blockIdx.x * 8 + (threadIdx.x >> 5);
    const int l32 = threadIdx.x & 31;
    const float* src;
    unsigned short* dst;
    float scale;
    float* norm;
    if (row < N_PRED) {
        src = pred + (size_t)row * KD;
        dst = predB + (size_t)row * KD;
        scale = -2.0f;                    // fold "-2 a.b" into A
        norm = a2 + row;
    } else {
        const int rr = row - N_PRED;
        src = tgt + (size_t)rr * KD;
        dst = tgtB + (size_t)rr * KD;
        scale = 1.0f;
        norm = b2 + rr;
    }
    const float4 x = reinterpret_cast<const float4*>(src)[l32];
    uint2 p;
    p.x = (unsigned int)f2bf(x.x * scale) | ((unsigned int)f2bf(x.y * scale) << 16);
    p.y = (unsigned int)f2bf(x.z * scale) | ((unsigned int)f2bf(x.w * scale) << 16);
    reinterpret_cast<uint2*>(dst)[l32] = p;
    float s = x.x * x.x + x.y * x.y + x.z * x.z + x.w * x.w;  // fp32 norms
    #pragma unroll
    for (int off = 16; off > 0; off >>= 1) s += __shfl_down(s, off, 32);
    if (l32 == 0) norm[0] = s;
    if (blockIdx.x == 0 && threadIdx.x == 0) { acc[0] = 0.0f; counter[0] = 0u; }
}

// ---- main: LDS-staged B tiles shared by 8 waves; 32 rows/wave; shfl merge ----
__global__ __launch_bounds__(512, 2) void density_kernel(
        const unsigned short* __restrict__ predB,
        const unsigned short* __restrict__ tgtB,
        const float* __restrict__ b2,
        float* __restrict__ wsTop) {
    const int tid   = threadIdx.x;
    const int wave  = tid >> 6;
    const int lane  = tid & 63;
    const int col   = lane & 15;
    const int quad  = lane >> 4;
    const int split = blockIdx.x & (SPLITS - 1);  // == XCD id mod 8 -> L2 locality
    const int rowblk = blockIdx.x >> 3;
    const int r0 = rowblk * ROWS_PER_BLOCK + wave * 32;
    const int m0 = split * MSPLIT;

    __shared__ short8 frag[2][TILE_T * 16];   // [buf][(g*4+kf)*64 + lane] : 32 KB
    __shared__ float  b2s[2][TILE_T];         // 512 B

    // A fragments for 2 row-sets of 16: A[m=lane&15][k=quad*8+j]
    short8 afrag[2][4];
    #pragma unroll
    for (int rf = 0; rf < 2; rf++)
        #pragma unroll
        for (int kf = 0; kf < 4; kf++)
            afrag[rf][kf] = *reinterpret_cast<const short8*>(
                predB + (size_t)(r0 + rf * 16 + col) * KD + kf * 32 + quad * 8);

    float t5[2][4][5];
    #pragma unroll
    for (int rf = 0; rf < 2; rf++)
        #pragma unroll
        for (int rg = 0; rg < 4; rg++)
            #pragma unroll
            for (int j = 0; j < 5; j++)
                t5[rf][rg][j] = FLT_MAX;

    // stage tile 0
    {
        const int m0t = m0;
        #pragma unroll
        for (int s = 0; s < 2; ++s) {
            const int ci = wave * 2 + s, g = ci >> 2, kf = ci & 3;
            const unsigned short* src =
                tgtB + (size_t)(m0t + g * 16 + col) * KD + kf * 32 + quad * 8;
            async16(src, &frag[0][ci * 64]);
        }
        if (wave == 0) async4(b2 + m0t + lane, &b2s[0][0]);
    }
    __syncthreads();

    for (int t = 0; t < NTILES; ++t) {
        const int cur = t & 1;
        if (t + 1 < NTILES) {                 // stage next tile (async)
            const int m0t = m0 + (t + 1) * TILE_T;
            #pragma unroll
            for (int s = 0; s < 2; ++s) {
                const int ci = wave * 2 + s, g = ci >> 2, kf = ci & 3;
                const unsigned short* src =
                    tgtB + (size_t)(m0t + g * 16 + col) * KD + kf * 32 + quad * 8;
                async16(src, &frag[cur ^ 1][ci * 64]);
            }
            if (wave == 0) async4(b2 + m0t + lane, &b2s[cur ^ 1][0]);
        }

        #pragma unroll
        for (int g = 0; g < 4; ++g) {
            const float bq = b2s[cur][g * 16 + col];
            short8 bf[4];
            #pragma unroll
            for (int kf = 0; kf < 4; ++kf)
                bf[kf] = frag[cur][(g * 4 + kf) * 64 + lane];  // sequential ds_read_b128
            #pragma unroll
            for (int rf = 0; rf < 2; ++rf) {
                floatx4 c = {bq, bq, bq, bq};  // seed |b|^2 (|a|^2 deferred)
                c = __builtin_amdgcn_mfma_f32_16x16x32_bf16(afrag[rf][0], bf[0], c, 0, 0, 0);
                c = __builtin_amdgcn_mfma_f32_16x16x32_bf16(afrag[rf][1], bf[1], c, 0, 0, 0);
                c = __builtin_amdgcn_mfma_f32_16x16x32_bf16(afrag[rf][2], bf[2], c, 0, 0, 0);
                c = __builtin_amdgcn_mfma_f32_16x16x32_bf16(afrag[rf][3], bf[3], c, 0, 0, 0);
                #pragma unroll
                for (int rg = 0; rg < 4; ++rg) ins5(t5[rf][rg], c[rg]);
            }
        }
        __syncthreads();   // drains staging vmcnt; guards buffer reuse
    }

    // butterfly merge across the 16 col-lanes (same quad group)
    #pragma unroll
    for (int off = 1; off < 16; off <<= 1) {
        #pragma unroll
        for (int rf = 0; rf < 2; ++rf)
            #pragma unroll
            for (int rg = 0; rg < 4; ++rg) {
                float o0 = __shfl_xor(t5[rf][rg][0], off);
                float o1 = __shfl_xor(t5[rf][rg][1], off);
                float o2 = __shfl_xor(t5[rf][rg][2], off);
                float o3 = __shfl_xor(t5[rf][rg][3], off);
                float o4 = __shfl_xor(t5[rf][rg][4], off);
                ins5(t5[rf][rg], o0); ins5(t5[rf][rg], o1); ins5(t5[rf][rg], o2);
                ins5(t5[rf][rg], o3); ins5(t5[rf][rg], o4);
            }
    }

    if (col == 0) {  // lanes 0,16,32,48 write rows quad*4+rg of each row-set
        #pragma unroll
        for (int rf = 0; rf < 2; ++rf)
            #pragma unroll
            for (int rg = 0; rg < 4; ++rg) {
                const int row = r0 + rf * 16 + quad * 4 + rg;
                float* dst = wsTop + ((size_t)row * SPLITS + split) * 5;
                #pragma unroll
                for (int j = 0; j < 5; ++j) dst[j] = t5[rf][rg][j];
            }
    }
}

// ---- merge: top-5 of 8 splits, hinge, global mean (fused finalize) -----------
__global__ void merge_kernel(const float* __restrict__ wsTop,
                             const float* __restrict__ a2,
                             float* __restrict__ acc,
                             unsigned int* __restrict__ counter,
                             float* __restrict__ out) {
    const int row = blockIdx.x * 256 + threadIdx.x;
    const float* p = wsTop + (size_t)row * (SPLITS * 5);
    float u[5] = {FLT_MAX, FLT_MAX, FLT_MAX, FLT_MAX, FLT_MAX};
    #pragma unroll
    for (int i = 0; i < SPLITS * 5; ++i) ins5(u, p[i]);
    const float a = a2[row];
    float hs = 0.0f;
    #pragma unroll
    for (int j = 0; j < 5; ++j) {
        const float dd = sqrtf(fmaxf(u[j] + a, 0.0f));
        hs += fmaxf(dd - 1.0f, 0.0f);
    }
    #pragma unroll
    for (int off = 32; off > 0; off >>= 1) hs += __shfl_down(hs, off);
    __shared__ float ws[4];
    if ((threadIdx.x & 63) == 0) ws[threadIdx.x >> 6] = hs;
    __syncthreads();
    if (threadIdx.x == 0) {
        atomicAdd(acc, ws[0] + ws[1] + ws[2] + ws[3]);
        __threadfence();
        const unsigned int done = atomicAdd(counter, 1u);
        if (done == gridDim.x - 1) {
            const float tot = atomicAdd(acc, 0.0f);   // atomic read: full sum
            out[0] = tot * (1.0f / (float)(N_PRED * TOPK));
        }
    }
}

extern "C" void kernel_launch(void* const* d_in, const int* in_sizes, int n_in,
                              void* d_out, int out_size, void* d_ws, size_t ws_size,
                              hipStream_t stream) {
    const float* pred = (const float*)d_in[0];
    const float* tgt  = (const float*)d_in[1];
    char* ws = (char*)d_ws;
    // ws: predB 2MB | tgtB 4MB @2M | a2 32KB @6M | b2 64KB | acc | counter | wsTop @7M (1.31MB)
    unsigned short* predB = (unsigned short*)(ws);
    unsigned short* tgtB  = (unsigned short*)(ws + (size_t)2 * 1024 * 1024);
    float* a2   = (float*)(ws + (size_t)6 * 1024 * 1024);
    float* b2   = (float*)(ws + (size_t)6 * 1024 * 1024 + 32 * 1024);
    float* acc  = (float*)(ws + (size_t)6 * 1024 * 1024 + 96 * 1024);
    unsigned int* counter = (unsigned int*)(ws + (size_t)6 * 1024 * 1024 + 96 * 1024 + 64);
    float* wsTop = (float*)(ws + (size_t)7 * 1024 * 1024);
    float* out = (float*)d_out;

    prep_kernel<<<(N_PRED + M_TGT) / 8, 256, 0, stream>>>(pred, tgt, predB, tgtB, a2, b2, acc, counter);
    density_kernel<<<ROWBLKS * SPLITS, 512, 0, stream>>>(predB, tgtB, b2, wsTop);
    merge_kernel<<<N_PRED / 256, 256, 0, stream>>>(wsTop, a2, acc, counter, out);
}

// Round 4
// 125.784 us; speedup vs baseline: 2.3716x; 1.0711x over previous
//
#include <hip/hip_runtime.h>
#include <hip/hip_bf16.h>
#include <float.h>

#define N_PRED 8192
#define M_TGT  16384
#define KD     128
#define TOPK   5
#define SPLITS 16
#define MSPLIT (M_TGT / SPLITS)            // 1024 targets per block
#define TILE_T 128                         // targets per LDS tile
#define NTILES (MSPLIT / TILE_T)           // 8
#define ROWS_PER_BLOCK 256                 // 8 waves x 32 rows
#define ROWBLKS (N_PRED / ROWS_PER_BLOCK)  // 32

using short8  = __attribute__((ext_vector_type(8))) short;
using floatx4 = __attribute__((ext_vector_type(4))) float;

__device__ __forceinline__ unsigned short f2bf(float v) {
    unsigned int u = __float_as_uint(v);
    u = (u + 0x7FFFu + ((u >> 16) & 1u)) >> 16;
    return (unsigned short)u;
}

// async global->LDS, dest = wave-uniform base + lane*size
__device__ __forceinline__ void async16(const void* g, void* l) {
    __builtin_amdgcn_global_load_lds(
        (const __attribute__((address_space(1))) unsigned int*)g,
        (__attribute__((address_space(3))) unsigned int*)l, 16, 0, 0);
}
__device__ __forceinline__ void async4(const void* g, void* l) {
    __builtin_amdgcn_global_load_lds(
        (const __attribute__((address_space(1))) unsigned int*)g,
        (__attribute__((address_space(3))) unsigned int*)l, 4, 0, 0);
}

// sorted ascending top-5 insert: 4x v_med3_f32 + 1x v_min_f32
__device__ __forceinline__ void ins5(float* t, float d) {
    t[4] = __builtin_amdgcn_fmed3f(d, t[3], t[4]);
    t[3] = __builtin_amdgcn_fmed3f(d, t[2], t[3]);
    t[2] = __builtin_amdgcn_fmed3f(d, t[1], t[2]);
    t[1] = __builtin_amdgcn_fmed3f(d, t[0], t[1]);
    t[0] = fminf(t[0], d);
}

// ---- prep: bf16 casts (pred pre-scaled by -2), fp32 norms, zero acc/counter --
__global__ void prep_kernel(const float* __restrict__ pred,
                            const float* __restrict__ tgt,
                            unsigned short* __restrict__ predB,
                            unsigned short* __restrict__ tgtB,
                            float* __restrict__ a2,
                            float* __restrict__ b2,
                            float* __restrict__ acc,
                            unsigned int* __restrict__ counter) {
    const int row = blockIdx.x * 8 + (threadIdx.x >> 5);
    const int l32 = threadIdx.x & 31;
    const float* src;
    unsigned short* dst;
    float scale;
    float* norm;
    if (row < N_PRED) {
        src = pred + (size_t)row * KD;
        dst = predB + (size_t)row * KD;
        scale = -2.0f;                    // fold "-2 a.b" into A
        norm = a2 + row;
    } else {
        const int rr = row - N_PRED;
        src = tgt + (size_t)rr * KD;
        dst = tgtB + (size_t)rr * KD;
        scale = 1.0f;
        norm = b2 + rr;
    }
    const float4 x = reinterpret_cast<const float4*>(src)[l32];
    uint2 p;
    p.x = (unsigned int)f2bf(x.x * scale) | ((unsigned int)f2bf(x.y * scale) << 16);
    p.y = (unsigned int)f2bf(x.z * scale) | ((unsigned int)f2bf(x.w * scale) << 16);
    reinterpret_cast<uint2*>(dst)[l32] = p;
    float s = x.x * x.x + x.y * x.y + x.z * x.z + x.w * x.w;  // fp32 norms
    #pragma unroll
    for (int off = 16; off > 0; off >>= 1) s += __shfl_down(s, off, 32);
    if (l32 == 0) norm[0] = s;
    if (blockIdx.x == 0 && threadIdx.x == 0) { acc[0] = 0.0f; counter[0] = 0u; }
}

// ---- main: LDS-staged B tiles shared by 8 waves; 32 rows/wave; shfl merge ----
__global__ __launch_bounds__(512, 4) void density_kernel(
        const unsigned short* __restrict__ predB,
        const unsigned short* __restrict__ tgtB,
        const float* __restrict__ b2,
        float* __restrict__ wsTop) {
    const int tid   = threadIdx.x;
    const int wave  = tid >> 6;
    const int lane  = tid & 63;
    const int col   = lane & 15;
    const int quad  = lane >> 4;
    const int split = blockIdx.x & (SPLITS - 1);  // same-XCD blocks share B chunks
    const int rowblk = blockIdx.x >> 4;
    const int r0 = rowblk * ROWS_PER_BLOCK + wave * 32;
    const int m0 = split * MSPLIT;

    __shared__ short8 frag[2][TILE_T * 16];   // [buf][(g*4+kf)*64 + lane] : 64 KB
    __shared__ float  b2s[2][TILE_T];         // 1 KB

    // A fragments for 2 row-sets of 16: A[m=lane&15][k=quad*8+j]
    short8 afrag[2][4];
    #pragma unroll
    for (int rf = 0; rf < 2; rf++)
        #pragma unroll
        for (int kf = 0; kf < 4; kf++)
            afrag[rf][kf] = *reinterpret_cast<const short8*>(
                predB + (size_t)(r0 + rf * 16 + col) * KD + kf * 32 + quad * 8);

    float t5[2][4][5];
    #pragma unroll
    for (int rf = 0; rf < 2; rf++)
        #pragma unroll
        for (int rg = 0; rg < 4; rg++)
            #pragma unroll
            for (int j = 0; j < 5; j++)
                t5[rf][rg][j] = FLT_MAX;

    // stage tile 0: 32 KB, 4 async16 per wave
    {
        #pragma unroll
        for (int s = 0; s < 4; ++s) {
            const int ci = wave * 4 + s, g = ci >> 2, kf = ci & 3;
            const unsigned short* src =
                tgtB + (size_t)(m0 + g * 16 + col) * KD + kf * 32 + quad * 8;
            async16(src, &frag[0][ci * 64]);
        }
        if (wave < 2) async4(b2 + m0 + wave * 64 + lane, &b2s[0][wave * 64]);
    }
    __syncthreads();

    for (int t = 0; t < NTILES; ++t) {
        const int cur = t & 1;
        if (t + 1 < NTILES) {                 // stage next tile (async)
            const int m0t = m0 + (t + 1) * TILE_T;
            #pragma unroll
            for (int s = 0; s < 4; ++s) {
                const int ci = wave * 4 + s, g = ci >> 2, kf = ci & 3;
                const unsigned short* src =
                    tgtB + (size_t)(m0t + g * 16 + col) * KD + kf * 32 + quad * 8;
                async16(src, &frag[cur ^ 1][ci * 64]);
            }
            if (wave < 2) async4(b2 + m0t + wave * 64 + lane, &b2s[cur ^ 1][wave * 64]);
        }

        #pragma unroll
        for (int g = 0; g < 8; ++g) {
            const float bq = b2s[cur][g * 16 + col];
            short8 bf[4];
            #pragma unroll
            for (int kf = 0; kf < 4; ++kf)
                bf[kf] = frag[cur][(g * 4 + kf) * 64 + lane];  // sequential ds_read_b128
            #pragma unroll
            for (int rf = 0; rf < 2; ++rf) {
                floatx4 c = {bq, bq, bq, bq};  // seed |b|^2 (|a|^2 deferred)
                c = __builtin_amdgcn_mfma_f32_16x16x32_bf16(afrag[rf][0], bf[0], c, 0, 0, 0);
                c = __builtin_amdgcn_mfma_f32_16x16x32_bf16(afrag[rf][1], bf[1], c, 0, 0, 0);
                c = __builtin_amdgcn_mfma_f32_16x16x32_bf16(afrag[rf][2], bf[2], c, 0, 0, 0);
                c = __builtin_amdgcn_mfma_f32_16x16x32_bf16(afrag[rf][3], bf[3], c, 0, 0, 0);
                #pragma unroll
                for (int rg = 0; rg < 4; ++rg) ins5(t5[rf][rg], c[rg]);
            }
        }
        __syncthreads();   // drains staging vmcnt; other resident block covers
    }

    // butterfly merge across the 16 col-lanes (same quad group)
    #pragma unroll
    for (int off = 1; off < 16; off <<= 1) {
        #pragma unroll
        for (int rf = 0; rf < 2; ++rf)
            #pragma unroll
            for (int rg = 0; rg < 4; ++rg) {
                float o0 = __shfl_xor(t5[rf][rg][0], off);
                float o1 = __shfl_xor(t5[rf][rg][1], off);
                float o2 = __shfl_xor(t5[rf][rg][2], off);
                float o3 = __shfl_xor(t5[rf][rg][3], off);
                float o4 = __shfl_xor(t5[rf][rg][4], off);
                ins5(t5[rf][rg], o0); ins5(t5[rf][rg], o1); ins5(t5[rf][rg], o2);
                ins5(t5[rf][rg], o3); ins5(t5[rf][rg], o4);
            }
    }

    if (col == 0) {  // lanes 0,16,32,48 hold rows quad*4+rg of each row-set
        #pragma unroll
        for (int rf = 0; rf < 2; ++rf)
            #pragma unroll
            for (int rg = 0; rg < 4; ++rg) {
                const int row = r0 + rf * 16 + quad * 4 + rg;
                float* dst = wsTop + ((size_t)row * SPLITS + split) * 5;
                #pragma unroll
                for (int j = 0; j < 5; ++j) dst[j] = t5[rf][rg][j];
            }
    }
}

// ---- merge: top-5 of 16 splits, hinge, global mean (fused finalize) ----------
__global__ void merge_kernel(const float* __restrict__ wsTop,
                             const float* __restrict__ a2,
                             float* __restrict__ acc,
                             unsigned int* __restrict__ counter,
                             float* __restrict__ out) {
    const int row = blockIdx.x * 256 + threadIdx.x;
    const float* p = wsTop + (size_t)row * (SPLITS * 5);
    float u[5] = {FLT_MAX, FLT_MAX, FLT_MAX, FLT_MAX, FLT_MAX};
    #pragma unroll
    for (int i = 0; i < SPLITS * 5; ++i) ins5(u, p[i]);
    const float a = a2[row];
    float hs = 0.0f;
    #pragma unroll
    for (int j = 0; j < 5; ++j) {
        const float dd = sqrtf(fmaxf(u[j] + a, 0.0f));
        hs += fmaxf(dd - 1.0f, 0.0f);
    }
    #pragma unroll
    for (int off = 32; off > 0; off >>= 1) hs += __shfl_down(hs, off);
    __shared__ float ws[4];
    if ((threadIdx.x & 63) == 0) ws[threadIdx.x >> 6] = hs;
    __syncthreads();
    if (threadIdx.x == 0) {
        atomicAdd(acc, ws[0] + ws[1] + ws[2] + ws[3]);
        __threadfence();
        const unsigned int done = atomicAdd(counter, 1u);
        if (done == gridDim.x - 1) {
            const float tot = atomicAdd(acc, 0.0f);   // atomic read: full sum
            out[0] = tot * (1.0f / (float)(N_PRED * TOPK));
        }
    }
}

extern "C" void kernel_launch(void* const* d_in, const int* in_sizes, int n_in,
                              void* d_out, int out_size, void* d_ws, size_t ws_size,
                              hipStream_t stream) {
    const float* pred = (const float*)d_in[0];
    const float* tgt  = (const float*)d_in[1];
    char* ws = (char*)d_ws;
    // ws: predB 2MB @0 | tgtB 4MB @2M | a2 32KB @6M | b2 64KB | acc | counter | wsTop @6M+128K (2.62MB)
    unsigned short* predB = (unsigned short*)(ws);
    unsigned short* tgtB  = (unsigned short*)(ws + (size_t)2 * 1024 * 1024);
    float* a2   = (float*)(ws + (size_t)6 * 1024 * 1024);
    float* b2   = (float*)(ws + (size_t)6 * 1024 * 1024 + 32 * 1024);
    float* acc  = (float*)(ws + (size_t)6 * 1024 * 1024 + 96 * 1024);
    unsigned int* counter = (unsigned int*)(ws + (size_t)6 * 1024 * 1024 + 96 * 1024 + 64);
    float* wsTop = (float*)(ws + (size_t)6 * 1024 * 1024 + 128 * 1024);
    float* out = (float*)d_out;

    prep_kernel<<<(N_PRED + M_TGT) / 8, 256, 0, stream>>>(pred, tgt, predB, tgtB, a2, b2, acc, counter);
    density_kernel<<<ROWBLKS * SPLITS, 512, 0, stream>>>(predB, tgtB, b2, wsTop);
    merge_kernel<<<N_PRED / 256, 256, 0, stream>>>(wsTop, a2, acc, counter, out);
}